// Round 3
// baseline (640.364 us; speedup 1.0000x reference)
//
#include <hip/hip_runtime.h>

// ---------------- problem constants ----------------
#define M_DIM 2048        // tlen*batch
#define K_DIM 1024        // input_size
#define N_DIM 32000       // vocab
#define CVOCAB 120
#define AGENDA 100
#define SLEN 400
#define CTX 300
#define BATCH 16
#define OUT_STRIDE 32120  // vocab + cvocab
#define PAD_IDX 1

#define TM 256            // GEMM tile M
#define TN 256            // GEMM tile N
#define BK 64             // GEMM K-step
#define BUFSZ (TM * BK)   // ushorts per LDS tile buffer (32 KB)
#define NKT (K_DIM / BK)  // 16
#define MT (M_DIM / TM)   // 8
#define NT (N_DIM / TN)   // 125

typedef float f32x4_t  __attribute__((ext_vector_type(4)));
typedef __bf16 bf16x8_t __attribute__((ext_vector_type(8)));
typedef unsigned short u16x8_t __attribute__((ext_vector_type(8)));
typedef unsigned short u16x4_t __attribute__((ext_vector_type(4)));

// RNE fp32 -> bf16 (values are all normal, no NaN handling needed)
__device__ __forceinline__ unsigned short f2bf(float f) {
    union { float f; unsigned int u; } c; c.f = f;
    unsigned int u = c.u;
    u += 0x7FFFu + ((u >> 16) & 1u);
    return (unsigned short)(u >> 16);
}

// fp32 <-> fp16 (exp values in [0, ~60]: fp16-safe, 2^-11 rel err << tolerance)
__device__ __forceinline__ unsigned short f2h(float f) {
    _Float16 h = (_Float16)f;
    unsigned short u; __builtin_memcpy(&u, &h, 2); return u;
}
__device__ __forceinline__ float h2f(unsigned short u) {
    _Float16 h; __builtin_memcpy(&h, &u, 2); return (float)h;
}

// async 16B global->LDS (dest = wave-uniform base + lane*16)
__device__ __forceinline__ void async_copy16(const void* gsrc, void* ldst) {
    __builtin_amdgcn_global_load_lds(
        (__attribute__((address_space(1))) unsigned int*)(gsrc),
        (__attribute__((address_space(3))) unsigned int*)(ldst),
        16, 0, 0);
}

// ---------------- kernel 1: fp32 -> bf16 cast of W and hidden (grid-stride) ----------------
__global__ __launch_bounds__(256) void cast_bf16_kernel(
    const float4* __restrict__ W, const float4* __restrict__ H,
    unsigned short* __restrict__ Wb, unsigned short* __restrict__ Hb) {
    const size_t NW4 = (size_t)N_DIM * K_DIM / 4;   // 8,192,000
    const size_t NH4 = (size_t)M_DIM * K_DIM / 4;   // 524,288
    const size_t total = NW4 + NH4;
    const size_t stride = (size_t)gridDim.x * 256;
    for (size_t idx = (size_t)blockIdx.x * 256 + threadIdx.x; idx < total; idx += stride) {
        float4 v; unsigned short* dst;
        if (idx < NW4) { v = W[idx];        dst = Wb + idx * 4; }
        else           { v = H[idx - NW4];  dst = Hb + (idx - NW4) * 4; }
        u16x4_t o;
        o[0] = f2bf(v.x); o[1] = f2bf(v.y); o[2] = f2bf(v.z); o[3] = f2bf(v.w);
        *(u16x4_t*)dst = o;
    }
}

// ---------------- kernel 2: p_copy + copy_prob + out tail + rowsum zero ----------------
// copy_prob = (attn[:,CTX:]*p) @ src_map is independent of the GEMM -> computed
// here, off the critical tail. One wave per row (4 waves/block).
__global__ __launch_bounds__(256) void pcopy_copy_kernel(
    const float* __restrict__ hidden, const float* __restrict__ Wc,
    const float* __restrict__ bc, const float* __restrict__ attn,
    const float* __restrict__ src_map,
    float* __restrict__ out, float* __restrict__ out_tail,
    float* __restrict__ pcopy, float* __restrict__ rowsum) {
    const int row  = blockIdx.x * 4 + (threadIdx.x >> 6);
    const int lane = threadIdx.x & 63;
    const float4* h = (const float4*)(hidden + (size_t)row * K_DIM);
    const float4* w = (const float4*)Wc;
    float s = 0.f;
    #pragma unroll
    for (int i = 0; i < 4; ++i) {
        float4 a = h[lane + 64 * i];
        float4 b = w[lane + 64 * i];
        s += a.x * b.x + a.y * b.y + a.z * b.z + a.w * b.w;
    }
    #pragma unroll
    for (int m = 1; m < 64; m <<= 1) s += __shfl_xor(s, m);   // all lanes get sum
    const float p = 1.0f / (1.0f + __expf(-(s + bc[0])));
    if (lane == 0) {
        pcopy[row]   = p;
        out_tail[row] = p;
        rowsum[row]  = 0.0f;    // ws is poisoned every call
    }
    // copy_prob: lane t covers cvocab columns t and t+64
    const int bidx = row & (BATCH - 1);
    const float* arow = attn + (size_t)row * SLEN + CTX;
    float s0 = 0.f, s1 = 0.f;
    #pragma unroll 4
    for (int a = 0; a < AGENDA; ++a) {
        float m = arow[a];                           // wave-uniform broadcast, L1-hit
        const float* sm = src_map + (size_t)(a * BATCH + bidx) * CVOCAB;
        s0 += m * sm[lane];
        if (lane < CVOCAB - 64) s1 += m * sm[lane + 64];
    }
    float* orow = out + (size_t)row * OUT_STRIDE + N_DIM;
    orow[lane] = s0 * p;
    if (lane < CVOCAB - 64) orow[lane + 64] = s1 * p;
}

// ---------------- kernel 3: GEMM + exp + row-sum (R1 structure: 256x256, 16 waves) ----------------
// Minimal double-buffer (stage k+1 before computing k). Writes exp as fp16 to E
// (row stride eStride u16): workspace buffer normally, out rows in fallback mode.
__global__ __launch_bounds__(1024, 4) void gemm_exp_kernel(
    const unsigned short* __restrict__ A,   // M x K bf16
    const unsigned short* __restrict__ B,   // N x K bf16
    const float* __restrict__ bias,         // N
    unsigned short* __restrict__ E,         // fp16 exp output
    const size_t eStride,                   // row stride in u16 units
    float* __restrict__ rowsum)             // M (zeroed by pcopy_copy_kernel)
{
    __shared__ unsigned short sA[2][BUFSZ]; // 64 KB
    __shared__ unsigned short sB[2][BUFSZ]; // 64 KB
    __shared__ float sRow[TM];              // 1 KB   (total 129 KB -> 1 block/CU)

    const int tid   = threadIdx.x;          // 0..1023
    const int lane  = tid & 63;
    const int q     = lane >> 4;
    const int lr    = lane & 15;
    const int wv    = tid >> 6;             // 0..15
    const int waveM = wv >> 2;              // 0..3 -> 64-row quarter
    const int waveN = wv & 3;               // 0..3 -> 64-col quarter

    // XCD swizzle: each XCD walks its 125 tiles M-fastest (B-panel L2 reuse)
    const int bid = blockIdx.x;
    const int t   = (bid & 7) * NT + (bid >> 3);   // 1000 = 8*125: bijective
    const int rowBase = (t & 7) * TM;
    const int colBase = (t >> 3) * TN;

    f32x4_t acc[4][4] = {};
    if (tid < TM) sRow[tid] = 0.0f;

    // Staging: tile = 256 rows x 64 k (128B/row = 8 chunks of 16B) = 2048 chunks, 2/thread.
    // LDS chunk slot s holds source chunk s ^ (row&7)  (XOR swizzle: conflict-free reads)
    const int p0 = tid,        m0 = p0 >> 3, j0 = (p0 & 7) ^ (m0 & 7);
    const int p1 = 1024 + tid, m1 = p1 >> 3, j1 = (p1 & 7) ^ (m1 & 7);
    const unsigned short* aSrc0 = A + (size_t)(rowBase + m0) * K_DIM + j0 * 8;
    const unsigned short* aSrc1 = A + (size_t)(rowBase + m1) * K_DIM + j1 * 8;
    const unsigned short* bSrc0 = B + (size_t)(colBase + m0) * K_DIM + j0 * 8;
    const unsigned short* bSrc1 = B + (size_t)(colBase + m1) * K_DIM + j1 * 8;
    const int dOff0 = (tid & ~63) * 8;
    const int dOff1 = (1024 + (tid & ~63)) * 8;

    // prologue: stage tile 0 into buffer 0 (syncthreads drains vmcnt)
    async_copy16(aSrc0, &sA[0][dOff0]);
    async_copy16(aSrc1, &sA[0][dOff1]);
    async_copy16(bSrc0, &sB[0][dOff0]);
    async_copy16(bSrc1, &sB[0][dOff1]);
    __syncthreads();

    for (int kt = 0; kt < NKT; ++kt) {
        const int cur = kt & 1;
        if (kt + 1 < NKT) {       // issue next tile's loads BEFORE computing this one
            const int nb = cur ^ 1;
            const int k0 = (kt + 1) * BK;
            async_copy16(aSrc0 + k0, &sA[nb][dOff0]);
            async_copy16(aSrc1 + k0, &sA[nb][dOff1]);
            async_copy16(bSrc0 + k0, &sB[nb][dOff0]);
            async_copy16(bSrc1 + k0, &sB[nb][dOff1]);
        }
        const unsigned short* pA = sA[cur];
        const unsigned short* pB = sB[cur];
        #pragma unroll
        for (int s = 0; s < 2; ++s) {   // two 16x16x32 K-steps
            u16x8_t af[4], bfr[4];
            #pragma unroll
            for (int r = 0; r < 4; ++r) {
                int m  = waveM * 64 + r * 16 + lr;
                int ch = (s * 4 + q) ^ (m & 7);
                af[r] = *(const u16x8_t*)(pA + m * BK + ch * 8);
            }
            #pragma unroll
            for (int c = 0; c < 4; ++c) {
                int n  = waveN * 64 + c * 16 + lr;
                int ch = (s * 4 + q) ^ (n & 7);
                bfr[c] = *(const u16x8_t*)(pB + n * BK + ch * 8);
            }
            #pragma unroll
            for (int r = 0; r < 4; ++r)
                #pragma unroll
                for (int c = 0; c < 4; ++c)
                    acc[r][c] = __builtin_amdgcn_mfma_f32_16x16x32_bf16(
                        __builtin_bit_cast(bf16x8_t, af[r]),
                        __builtin_bit_cast(bf16x8_t, bfr[c]),
                        acc[r][c], 0, 0, 0);
        }
        __syncthreads();  // drains this iter's prefetch (vmcnt 0) + read-protects buffers
    }

    // epilogue: C/D layout col=lane&15 (vocab n), row=quad*4+reg (token m)
    float bb[4];
    #pragma unroll
    for (int c = 0; c < 4; ++c) bb[c] = bias[colBase + waveN * 64 + c * 16 + lr];

    #pragma unroll
    for (int r = 0; r < 4; ++r) {
        float rsum[4] = {0.f, 0.f, 0.f, 0.f};
        #pragma unroll
        for (int c = 0; c < 4; ++c) {
            int gcol = colBase + waveN * 64 + c * 16 + lr;
            bool pad = (gcol == PAD_IDX);
            #pragma unroll
            for (int d = 0; d < 4; ++d) {
                int grow = rowBase + waveM * 64 + r * 16 + q * 4 + d;
                float e = pad ? 0.0f : __expf(acc[r][c][d] + bb[c]);
                E[(size_t)grow * eStride + gcol] = f2h(e);
                rsum[d] += e;
            }
        }
        #pragma unroll
        for (int d = 0; d < 4; ++d) {
            float v = rsum[d];
            v += __shfl_xor(v, 1);
            v += __shfl_xor(v, 2);
            v += __shfl_xor(v, 4);
            v += __shfl_xor(v, 8);
            if (lr == 0) {
                int lrow = waveM * 64 + r * 16 + q * 4 + d;
                atomicAdd(&sRow[lrow], v);   // LDS atomic: 4x fewer global atomics
            }
        }
    }
    __syncthreads();
    if (tid < TM) atomicAdd(&rowsum[rowBase + tid], sRow[tid]);
}

// ---------------- kernel 4a: pure-streaming normalize (E in workspace) ----------------
// No LDS, no barrier: read fp16 E row, write normalized fp32 vocab region.
__global__ __launch_bounds__(256) void normalize_kernel(
    const unsigned short* __restrict__ E, float* __restrict__ out,
    const float* __restrict__ rowsum, const float* __restrict__ pcopy) {
    const int n   = blockIdx.x;
    const int tid = threadIdx.x;
    const float scale = (1.0f - pcopy[n]) / rowsum[n];
    const u16x8_t* src = (const u16x8_t*)(E + (size_t)n * N_DIM);
    float4* dst = (float4*)(out + (size_t)n * OUT_STRIDE);
    for (int j = tid; j < N_DIM / 8; j += 256) {   // 16B load + 32B store per iter
        u16x8_t h = src[j];
        float4 a, b;
        a.x = h2f(h[0]) * scale; a.y = h2f(h[1]) * scale;
        a.z = h2f(h[2]) * scale; a.w = h2f(h[3]) * scale;
        b.x = h2f(h[4]) * scale; b.y = h2f(h[5]) * scale;
        b.z = h2f(h[6]) * scale; b.w = h2f(h[7]) * scale;
        dst[j * 2]     = a;
        dst[j * 2 + 1] = b;
    }
}

// ---------------- kernel 4b: fallback in-place normalize (fp16 packed in out rows) ----------------
__global__ __launch_bounds__(512) void normalize_inplace_kernel(
    float* __restrict__ out, const float* __restrict__ rowsum,
    const float* __restrict__ pcopy) {
    const int n   = blockIdx.x;
    const int tid = threadIdx.x;
    __shared__ unsigned short sE[N_DIM];   // 64000 B
    const float scale = (1.0f - pcopy[n]) / rowsum[n];
    const u16x8_t* src = (const u16x8_t*)(out + (size_t)n * OUT_STRIDE);
    for (int j = tid; j < N_DIM / 8; j += 512)
        *(u16x8_t*)(sE + j * 8) = src[j];
    __syncthreads();
    float4* row4 = (float4*)(out + (size_t)n * OUT_STRIDE);
    for (int j = tid; j < N_DIM / 4; j += 512) {
        u16x4_t h = *(const u16x4_t*)(sE + j * 4);
        float4 v;
        v.x = h2f(h[0]) * scale;
        v.y = h2f(h[1]) * scale;
        v.z = h2f(h[2]) * scale;
        v.w = h2f(h[3]) * scale;
        row4[j] = v;
    }
}

// ---------------- launch ----------------
extern "C" void kernel_launch(void* const* d_in, const int* in_sizes, int n_in,
                              void* d_out, int out_size, void* d_ws, size_t ws_size,
                              hipStream_t stream) {
    const float* hidden  = (const float*)d_in[0];
    const float* attn    = (const float*)d_in[1];
    const float* src_map = (const float*)d_in[2];
    const float* W       = (const float*)d_in[3];
    const float* b       = (const float*)d_in[4];
    const float* W_copy  = (const float*)d_in[5];
    const float* b_copy  = (const float*)d_in[6];
    float* out = (float*)d_out;

    // workspace layout
    char* ws = (char*)d_ws;
    unsigned short* Wb = (unsigned short*)ws;                               // 65,536,000 B
    unsigned short* Hb = (unsigned short*)(ws + 65536000);                  //  4,194,304 B
    float* rowsum      = (float*)(ws + 65536000 + 4194304);                 //      8,192 B
    float* pcopy       = (float*)(ws + 65536000 + 4194304 + 8192);          //      8,192 B
    unsigned short* E  = (unsigned short*)(ws + 65536000 + 4194304 + 16384);// 131,072,000 B
    const size_t wsNeeded = 65536000ull + 4194304 + 16384 + (size_t)M_DIM * N_DIM * 2;
    const bool useWsE = (ws_size >= wsNeeded);

    float* out_tail = out + (size_t)M_DIM * OUT_STRIDE;  // p_copy output

    // 1. cast W + hidden to bf16 (grid-stride, 2048 blocks)
    cast_bf16_kernel<<<2048, 256, 0, stream>>>((const float4*)W, (const float4*)hidden, Wb, Hb);
    // 2. p_copy + copy_prob + tail + rowsum zero (independent of GEMM)
    pcopy_copy_kernel<<<M_DIM / 4, 256, 0, stream>>>(hidden, W_copy, b_copy, attn, src_map,
                                                     out, out_tail, pcopy, rowsum);
    // 3. GEMM + exp + rowsum
    if (useWsE) {
        gemm_exp_kernel<<<MT * NT, 1024, 0, stream>>>(Hb, Wb, b, E, (size_t)N_DIM, rowsum);
        // 4a. pure streaming normalize
        normalize_kernel<<<M_DIM, 256, 0, stream>>>(E, out, rowsum, pcopy);
    } else {
        gemm_exp_kernel<<<MT * NT, 1024, 0, stream>>>(Hb, Wb, b, (unsigned short*)out,
                                                      (size_t)OUT_STRIDE * 2, rowsum);
        // 4b. in-place normalize (LDS-staged)
        normalize_inplace_kernel<<<M_DIM, 512, 0, stream>>>(out, rowsum, pcopy);
    }
}

// Round 4
// 590.682 us; speedup vs baseline: 1.0841x; 1.0841x over previous
//
#include <hip/hip_runtime.h>

// ---------------- problem constants ----------------
#define M_DIM 2048        // tlen*batch
#define K_DIM 1024        // input_size
#define N_DIM 32000       // vocab
#define CVOCAB 120
#define AGENDA 100
#define SLEN 400
#define CTX 300
#define BATCH 16
#define OUT_STRIDE 32120  // vocab + cvocab
#define PAD_IDX 1

#define TM 256            // GEMM tile M
#define TN 256            // GEMM tile N
#define BK 64             // GEMM K-step
#define BUFSZ (TM * BK)   // ushorts per LDS tile buffer (32 KB)
#define NKT (K_DIM / BK)  // 16
#define MT (M_DIM / TM)   // 8
#define NT (N_DIM / TN)   // 125

typedef float f32x4_t  __attribute__((ext_vector_type(4)));
typedef __bf16 bf16x8_t __attribute__((ext_vector_type(8)));
typedef unsigned short u16x8_t __attribute__((ext_vector_type(8)));
typedef unsigned short u16x4_t __attribute__((ext_vector_type(4)));
typedef unsigned int   u32x4_t __attribute__((ext_vector_type(4)));

// RNE fp32 -> bf16 (values are all normal, no NaN handling needed)
__device__ __forceinline__ unsigned short f2bf(float f) {
    union { float f; unsigned int u; } c; c.f = f;
    unsigned int u = c.u;
    u += 0x7FFFu + ((u >> 16) & 1u);
    return (unsigned short)(u >> 16);
}

// packed RNE fp32x2 -> bf16x2 (low = lo arg). T12 recipe: no builtin on gfx950.
__device__ __forceinline__ unsigned int cvt_pk_bf16(float lo, float hi) {
    unsigned int r;
    asm("v_cvt_pk_bf16_f32 %0, %1, %2" : "=v"(r) : "v"(lo), "v"(hi));
    return r;
}

// fp32 <-> fp16 (exp values in [0, ~60]: fp16-safe, 2^-11 rel err << tolerance)
__device__ __forceinline__ unsigned short f2h(float f) {
    _Float16 h = (_Float16)f;
    unsigned short u; __builtin_memcpy(&u, &h, 2); return u;
}
__device__ __forceinline__ float h2f(unsigned short u) {
    _Float16 h; __builtin_memcpy(&h, &u, 2); return (float)h;
}

// async 16B global->LDS (dest = wave-uniform base + lane*16)
__device__ __forceinline__ void async_copy16(const void* gsrc, void* ldst) {
    __builtin_amdgcn_global_load_lds(
        (__attribute__((address_space(1))) unsigned int*)(gsrc),
        (__attribute__((address_space(3))) unsigned int*)(ldst),
        16, 0, 0);
}

// ---------------- kernel 1: p_copy + hidden->bf16 + copy_prob + tail + rowsum zero ----
// One wave per row (4 waves/block). The wave reads its full hidden row once:
// dot with W_copy AND emit the bf16 copy of the row (replaces the W/H cast
// kernel's H-half; the W-half is eliminated entirely — GEMM reads W fp32).
__global__ __launch_bounds__(256) void pcopy_cast_kernel(
    const float* __restrict__ hidden, const float* __restrict__ Wc,
    const float* __restrict__ bc, const float* __restrict__ attn,
    const float* __restrict__ src_map, unsigned short* __restrict__ Hb,
    float* __restrict__ out, float* __restrict__ out_tail,
    float* __restrict__ pcopy, float* __restrict__ rowsum) {
    const int row  = blockIdx.x * 4 + (threadIdx.x >> 6);
    const int lane = threadIdx.x & 63;
    const float4* h = (const float4*)(hidden + (size_t)row * K_DIM);
    const float4* w = (const float4*)Wc;
    float s = 0.f;
    #pragma unroll
    for (int i = 0; i < 4; ++i) {
        float4 a = h[lane + 64 * i];
        float4 b = w[lane + 64 * i];
        s += a.x * b.x + a.y * b.y + a.z * b.z + a.w * b.w;
        u16x4_t o;
        o[0] = f2bf(a.x); o[1] = f2bf(a.y); o[2] = f2bf(a.z); o[3] = f2bf(a.w);
        *(u16x4_t*)(Hb + (size_t)row * K_DIM + (lane + 64 * i) * 4) = o;
    }
    #pragma unroll
    for (int m = 1; m < 64; m <<= 1) s += __shfl_xor(s, m);   // all lanes get sum
    const float p = 1.0f / (1.0f + __expf(-(s + bc[0])));
    if (lane == 0) {
        pcopy[row]    = p;
        out_tail[row] = p;
        rowsum[row]   = 0.0f;    // ws is poisoned every call
    }
    // copy_prob (independent of the GEMM): lane t covers cvocab cols t, t+64
    const int bidx = row & (BATCH - 1);
    const float* arow = attn + (size_t)row * SLEN + CTX;
    float s0 = 0.f, s1 = 0.f;
    #pragma unroll 4
    for (int a = 0; a < AGENDA; ++a) {
        float m = arow[a];                           // wave-uniform, L1-hit
        const float* sm = src_map + (size_t)(a * BATCH + bidx) * CVOCAB;
        s0 += m * sm[lane];
        if (lane < CVOCAB - 64) s1 += m * sm[lane + 64];
    }
    float* orow = out + (size_t)row * OUT_STRIDE + N_DIM;
    orow[lane] = s0 * p;
    if (lane < CVOCAB - 64) orow[lane + 64] = s1 * p;
}

// ---------------- kernel 2: GEMM + exp + row-sum (256x256 tile, 16 waves) ----------------
// A-path: bf16 via global_load_lds (unchanged R1 structure).
// B-path: W read as FP32 directly (no pre-cast kernel): reg-staged float4 loads
// issued at top of iter k for k+1 (T14: latency hides under MFMA), converted
// with v_cvt_pk_bf16_f32 and ds_write_b128 into the swizzled slots after the
// MFMA block. Reader side unchanged: slot (n,cs) holds source chunk cs^(n&7).
// Writes exp as fp16 IN-PLACE into the first 64000 B of each out row.
__global__ __launch_bounds__(1024, 4) void gemm_exp_kernel(
    const unsigned short* __restrict__ A,   // M x K bf16
    const float* __restrict__ Bf,           // N x K fp32 (= W)
    const float* __restrict__ bias,         // N
    float* __restrict__ out,                // row stride OUT_STRIDE (fp16 staging)
    float* __restrict__ rowsum)             // M (zeroed by pcopy_cast_kernel)
{
    __shared__ unsigned short sA[2][BUFSZ]; // 64 KB
    __shared__ unsigned short sB[2][BUFSZ]; // 64 KB
    __shared__ float sRow[TM];              // 1 KB   (129 KB -> 1 block/CU, 16 waves)

    const int tid   = threadIdx.x;          // 0..1023
    const int lane  = tid & 63;
    const int q     = lane >> 4;
    const int lr    = lane & 15;
    const int wv    = tid >> 6;             // 0..15
    const int waveM = wv >> 2;              // 0..3 -> 64-row quarter
    const int waveN = wv & 3;               // 0..3 -> 64-col quarter

    // XCD swizzle: each XCD walks its 125 tiles M-fastest (B-panel L2 reuse)
    const int bid = blockIdx.x;
    const int t   = (bid & 7) * NT + (bid >> 3);   // 1000 = 8*125: bijective
    const int rowBase = (t & 7) * TM;
    const int colBase = (t >> 3) * TN;

    f32x4_t acc[4][4] = {};
    if (tid < TM) sRow[tid] = 0.0f;

    // ---- A staging (global_load_lds): 2048 chunks of 16B, 2/thread ----
    // LDS chunk slot cs holds source chunk cs ^ (row&7)  (XOR swizzle)
    const int p0 = tid,        m0 = p0 >> 3, j0 = (p0 & 7) ^ (m0 & 7);
    const int p1 = 1024 + tid, m1 = p1 >> 3, j1 = (p1 & 7) ^ (m1 & 7);
    const unsigned short* aSrc0 = A + (size_t)(rowBase + m0) * K_DIM + j0 * 8;
    const unsigned short* aSrc1 = A + (size_t)(rowBase + m1) * K_DIM + j1 * 8;
    const int dOff0 = (tid & ~63) * 8;
    const int dOff1 = (1024 + (tid & ~63)) * 8;

    // ---- B staging (fp32 reg + cvt): thread owns source chunks {j_b, j_b+4}
    // of row n_b. Global reads: 32 B contiguous per lane, 128 B per 4 lanes.
    const int n_b = tid >> 2, j_b = tid & 3;
    const float4* bRow = (const float4*)(Bf + (size_t)(colBase + n_b) * K_DIM);
    const int csLo = j_b ^ (n_b & 7);          // dest slot for chunk j_b
    const int csHi = csLo ^ 4;                 // dest slot for chunk j_b+4
    const int bOffLo = n_b * BK + csLo * 8;    // u16 offsets within sB buffer
    const int bOffHi = n_b * BK + csHi * 8;

#define CVT_STORE(DST, A4, B4) do {                        \
        u32x4_t pk_;                                       \
        pk_[0] = cvt_pk_bf16((A4).x, (A4).y);              \
        pk_[1] = cvt_pk_bf16((A4).z, (A4).w);              \
        pk_[2] = cvt_pk_bf16((B4).x, (B4).y);              \
        pk_[3] = cvt_pk_bf16((B4).z, (B4).w);              \
        *(u32x4_t*)(DST) = pk_; } while (0)

    // prologue: stage tile 0
    {
        float4 l0 = bRow[j_b * 2], l1 = bRow[j_b * 2 + 1];
        float4 l2 = bRow[j_b * 2 + 8], l3 = bRow[j_b * 2 + 9];
        async_copy16(aSrc0, &sA[0][dOff0]);
        async_copy16(aSrc1, &sA[0][dOff1]);
        CVT_STORE(&sB[0][bOffLo], l0, l1);
        CVT_STORE(&sB[0][bOffHi], l2, l3);
    }
    __syncthreads();

    for (int kt = 0; kt < NKT; ++kt) {
        const int cur = kt & 1, nb = cur ^ 1;
        float4 l0, l1, l2, l3;
        if (kt + 1 < NKT) {
            // issue next tile's loads BEFORE computing this one (T14 issue-early)
            const int f4 = (kt + 1) * (BK / 4) + j_b * 2;
            l0 = bRow[f4];     l1 = bRow[f4 + 1];
            l2 = bRow[f4 + 8]; l3 = bRow[f4 + 9];
            const int k0 = (kt + 1) * BK;
            async_copy16(aSrc0 + k0, &sA[nb][dOff0]);
            async_copy16(aSrc1 + k0, &sA[nb][dOff1]);
        }
        const unsigned short* pA = sA[cur];
        const unsigned short* pB = sB[cur];
        #pragma unroll
        for (int s = 0; s < 2; ++s) {   // two 16x16x32 K-steps
            u16x8_t af[4], bfr[4];
            #pragma unroll
            for (int r = 0; r < 4; ++r) {
                int m  = waveM * 64 + r * 16 + lr;
                int ch = (s * 4 + q) ^ (m & 7);
                af[r] = *(const u16x8_t*)(pA + m * BK + ch * 8);
            }
            #pragma unroll
            for (int c = 0; c < 4; ++c) {
                int n  = waveN * 64 + c * 16 + lr;
                int ch = (s * 4 + q) ^ (n & 7);
                bfr[c] = *(const u16x8_t*)(pB + n * BK + ch * 8);
            }
            #pragma unroll
            for (int r = 0; r < 4; ++r)
                #pragma unroll
                for (int c = 0; c < 4; ++c)
                    acc[r][c] = __builtin_amdgcn_mfma_f32_16x16x32_bf16(
                        __builtin_bit_cast(bf16x8_t, af[r]),
                        __builtin_bit_cast(bf16x8_t, bfr[c]),
                        acc[r][c], 0, 0, 0);
        }
        if (kt + 1 < NKT) {
            // write-late: vmcnt wait here covers only the B regs (A's lds-DMA
            // stays in flight until the barrier); latency hid under the MFMAs
            CVT_STORE(&sB[nb][bOffLo], l0, l1);
            CVT_STORE(&sB[nb][bOffHi], l2, l3);
        }
        __syncthreads();  // drains A DMA + orders sB writes for next iter
    }
#undef CVT_STORE

    // epilogue: C/D layout col=lane&15 (vocab n), row=quad*4+reg (token m)
    float bb[4];
    #pragma unroll
    for (int c = 0; c < 4; ++c) bb[c] = bias[colBase + waveN * 64 + c * 16 + lr];

    #pragma unroll
    for (int r = 0; r < 4; ++r) {
        float rsum[4] = {0.f, 0.f, 0.f, 0.f};
        #pragma unroll
        for (int c = 0; c < 4; ++c) {
            int gcol = colBase + waveN * 64 + c * 16 + lr;
            bool pad = (gcol == PAD_IDX);
            #pragma unroll
            for (int d = 0; d < 4; ++d) {
                int grow = rowBase + waveM * 64 + r * 16 + q * 4 + d;
                float e = pad ? 0.0f : __expf(acc[r][c][d] + bb[c]);
                // fp16 in-place: first 64000 B of the row's fp32 region
                ((unsigned short*)(out + (size_t)grow * OUT_STRIDE))[gcol] = f2h(e);
                rsum[d] += e;
            }
        }
        #pragma unroll
        for (int d = 0; d < 4; ++d) {
            float v = rsum[d];
            v += __shfl_xor(v, 1);
            v += __shfl_xor(v, 2);
            v += __shfl_xor(v, 4);
            v += __shfl_xor(v, 8);
            if (lr == 0) {
                int lrow = waveM * 64 + r * 16 + q * 4 + d;
                atomicAdd(&sRow[lrow], v);   // LDS atomic: 4x fewer global atomics
            }
        }
    }
    __syncthreads();
    if (tid < TM) atomicAdd(&rowsum[rowBase + tid], sRow[tid]);
}

// ---------------- kernel 3: in-place normalize (fp16 packed in out rows) ----------------
// Stage the fp16 row in LDS, then expand to normalized fp32 in place. The RMW
// of the same lines keeps them LLC-resident (measured better than a separate
// E buffer, R3 post-mortem).
__global__ __launch_bounds__(512) void finalize_kernel(
    float* __restrict__ out, const float* __restrict__ rowsum,
    const float* __restrict__ pcopy) {
    const int n   = blockIdx.x;
    const int tid = threadIdx.x;
    __shared__ unsigned short sE[N_DIM];   // 64000 B
    const float scale = (1.0f - pcopy[n]) / rowsum[n];
    const u16x8_t* src = (const u16x8_t*)(out + (size_t)n * OUT_STRIDE);
    for (int j = tid; j < N_DIM / 8; j += 512)
        *(u16x8_t*)(sE + j * 8) = src[j];
    __syncthreads();
    float4* row4 = (float4*)(out + (size_t)n * OUT_STRIDE);
    for (int j = tid; j < N_DIM / 4; j += 512) {
        u16x4_t h = *(const u16x4_t*)(sE + j * 4);
        float4 v;
        v.x = h2f(h[0]) * scale;
        v.y = h2f(h[1]) * scale;
        v.z = h2f(h[2]) * scale;
        v.w = h2f(h[3]) * scale;
        row4[j] = v;
    }
}

// ---------------- launch ----------------
extern "C" void kernel_launch(void* const* d_in, const int* in_sizes, int n_in,
                              void* d_out, int out_size, void* d_ws, size_t ws_size,
                              hipStream_t stream) {
    const float* hidden  = (const float*)d_in[0];
    const float* attn    = (const float*)d_in[1];
    const float* src_map = (const float*)d_in[2];
    const float* W       = (const float*)d_in[3];
    const float* b       = (const float*)d_in[4];
    const float* W_copy  = (const float*)d_in[5];
    const float* b_copy  = (const float*)d_in[6];
    float* out = (float*)d_out;

    // workspace layout (tiny now: no Wb)
    char* ws = (char*)d_ws;
    unsigned short* Hb = (unsigned short*)ws;                 //  4,194,304 B
    float* rowsum      = (float*)(ws + 4194304);              //      8,192 B
    float* pcopy       = (float*)(ws + 4194304 + 8192);       //      8,192 B

    float* out_tail = out + (size_t)M_DIM * OUT_STRIDE;       // p_copy output

    // 1. p_copy + hidden->bf16 + copy_prob + tail + rowsum zero
    pcopy_cast_kernel<<<M_DIM / 4, 256, 0, stream>>>(hidden, W_copy, b_copy, attn,
                                                     src_map, Hb, out, out_tail,
                                                     pcopy, rowsum);
    // 2. GEMM + exp + rowsum  (reads W fp32 directly — no cast kernel)
    gemm_exp_kernel<<<MT * NT, 1024, 0, stream>>>(Hb, W, b, out, rowsum);
    // 3. in-place normalize
    finalize_kernel<<<M_DIM, 512, 0, stream>>>(out, rowsum, pcopy);
}

// Round 5
// 590.326 us; speedup vs baseline: 1.0848x; 1.0006x over previous
//
#include <hip/hip_runtime.h>

// ---------------- problem constants ----------------
#define M_DIM 2048        // tlen*batch
#define K_DIM 1024        // input_size
#define N_DIM 32000       // vocab
#define CVOCAB 120
#define AGENDA 100
#define SLEN 400
#define CTX 300
#define BATCH 16
#define OUT_STRIDE 32120  // vocab + cvocab
#define PAD_IDX 1

#define TM 256            // GEMM tile M
#define TN 256            // GEMM tile N
#define BK 64             // GEMM K-step
#define BUFSZ (TM * BK)   // ushorts per LDS tile buffer (32 KB)
#define NKT (K_DIM / BK)  // 16
#define MT (M_DIM / TM)   // 8
#define NT (N_DIM / TN)   // 125

// B-slot permutation: slot = chunk ^ BSWZ(row). Chosen so a quarter-wave of the
// writer (4 consecutive rows x 4 chunks) spreads over all 32 banks (2-deep,
// free) AND the reader (16 consecutive rows, fixed chunk) stays 2-deep.
// R4's (n&7) gave 4-deep writer quarters = 8 extra cyc/write = 4.1M conflicts.
#define BSWZ(n) ((((n) & 3) << 1) | (((n) >> 2) & 1))

typedef float f32x4_t  __attribute__((ext_vector_type(4)));
typedef __bf16 bf16x8_t __attribute__((ext_vector_type(8)));
typedef unsigned short u16x8_t __attribute__((ext_vector_type(8)));
typedef unsigned short u16x4_t __attribute__((ext_vector_type(4)));
typedef unsigned int   u32x4_t __attribute__((ext_vector_type(4)));

// RNE fp32 -> bf16 (values are all normal, no NaN handling needed)
__device__ __forceinline__ unsigned short f2bf(float f) {
    union { float f; unsigned int u; } c; c.f = f;
    unsigned int u = c.u;
    u += 0x7FFFu + ((u >> 16) & 1u);
    return (unsigned short)(u >> 16);
}

// packed RNE fp32x2 -> bf16x2 (low = lo arg). No builtin on gfx950.
__device__ __forceinline__ unsigned int cvt_pk_bf16(float lo, float hi) {
    unsigned int r;
    asm("v_cvt_pk_bf16_f32 %0, %1, %2" : "=v"(r) : "v"(lo), "v"(hi));
    return r;
}

// fp32 <-> fp16 (exp values in [0, ~60]: fp16-safe, 2^-11 rel err << tolerance)
__device__ __forceinline__ unsigned short f2h(float f) {
    _Float16 h = (_Float16)f;
    unsigned short u; __builtin_memcpy(&u, &h, 2); return u;
}
__device__ __forceinline__ float h2f(unsigned short u) {
    _Float16 h; __builtin_memcpy(&h, &u, 2); return (float)h;
}

// async 16B global->LDS (dest = wave-uniform base + lane*16)
__device__ __forceinline__ void async_copy16(const void* gsrc, void* ldst) {
    __builtin_amdgcn_global_load_lds(
        (__attribute__((address_space(1))) unsigned int*)(gsrc),
        (__attribute__((address_space(3))) unsigned int*)(ldst),
        16, 0, 0);
}

// ---------------- kernel 1: p_copy + hidden->bf16 + copy_prob + tail + rowsum zero ----
__global__ __launch_bounds__(256) void pcopy_cast_kernel(
    const float* __restrict__ hidden, const float* __restrict__ Wc,
    const float* __restrict__ bc, const float* __restrict__ attn,
    const float* __restrict__ src_map, unsigned short* __restrict__ Hb,
    float* __restrict__ out, float* __restrict__ out_tail,
    float* __restrict__ pcopy, float* __restrict__ rowsum) {
    const int row  = blockIdx.x * 4 + (threadIdx.x >> 6);
    const int lane = threadIdx.x & 63;
    const float4* h = (const float4*)(hidden + (size_t)row * K_DIM);
    const float4* w = (const float4*)Wc;
    float s = 0.f;
    #pragma unroll
    for (int i = 0; i < 4; ++i) {
        float4 a = h[lane + 64 * i];
        float4 b = w[lane + 64 * i];
        s += a.x * b.x + a.y * b.y + a.z * b.z + a.w * b.w;
        u16x4_t o;
        o[0] = f2bf(a.x); o[1] = f2bf(a.y); o[2] = f2bf(a.z); o[3] = f2bf(a.w);
        *(u16x4_t*)(Hb + (size_t)row * K_DIM + (lane + 64 * i) * 4) = o;
    }
    #pragma unroll
    for (int m = 1; m < 64; m <<= 1) s += __shfl_xor(s, m);   // all lanes get sum
    const float p = 1.0f / (1.0f + __expf(-(s + bc[0])));
    if (lane == 0) {
        pcopy[row]    = p;
        out_tail[row] = p;
        rowsum[row]   = 0.0f;    // ws is poisoned every call
    }
    // copy_prob (independent of the GEMM): lane t covers cvocab cols t, t+64
    const int bidx = row & (BATCH - 1);
    const float* arow = attn + (size_t)row * SLEN + CTX;
    float s0 = 0.f, s1 = 0.f;
    #pragma unroll 4
    for (int a = 0; a < AGENDA; ++a) {
        float m = arow[a];                           // wave-uniform, L1-hit
        const float* sm = src_map + (size_t)(a * BATCH + bidx) * CVOCAB;
        s0 += m * sm[lane];
        if (lane < CVOCAB - 64) s1 += m * sm[lane + 64];
    }
    float* orow = out + (size_t)row * OUT_STRIDE + N_DIM;
    orow[lane] = s0 * p;
    if (lane < CVOCAB - 64) orow[lane + 64] = s1 * p;
}

// ---------------- kernel 2: GEMM + exp + row-sum (256x256 tile, 16 waves) ----------------
// A-path: bf16 via global_load_lds. B-path: W fp32 reg-staged + cvt_pk + swizzled
// ds_write_b128 (BSWZ slots: conflict-free). Grid covers NCT col-tiles starting
// at colTileOff (launched twice so the 2nd-longest kernel becomes rocprof-visible).
__global__ __launch_bounds__(1024, 4) void gemm_exp_kernel(
    const unsigned short* __restrict__ A,   // M x K bf16
    const float* __restrict__ Bf,           // N x K fp32 (= W)
    const float* __restrict__ bias,         // N
    float* __restrict__ out,                // row stride OUT_STRIDE (fp16 staging)
    float* __restrict__ rowsum,             // M (zeroed by pcopy_cast_kernel)
    const int NCT, const int colTileOff)    // col-tile count / offset
{
    __shared__ unsigned short sA[2][BUFSZ]; // 64 KB
    __shared__ unsigned short sB[2][BUFSZ]; // 64 KB
    __shared__ float sRow[TM];              // 1 KB   (129 KB -> 1 block/CU, 16 waves)

    const int tid   = threadIdx.x;          // 0..1023
    const int lane  = tid & 63;
    const int q     = lane >> 4;
    const int lr    = lane & 15;
    const int wv    = tid >> 6;             // 0..15
    const int waveM = wv >> 2;              // 0..3 -> 64-row quarter
    const int waveN = wv & 3;               // 0..3 -> 64-col quarter

    // XCD swizzle: each XCD walks its NCT tiles M-fastest (B-panel L2 reuse).
    // Grid = 8*NCT (multiple of 8 -> bijective).
    const int bid = blockIdx.x;
    const int t   = (bid & 7) * NCT + (bid >> 3);
    const int rowBase = (t & 7) * TM;
    const int colBase = (colTileOff + (t >> 3)) * TN;

    f32x4_t acc[4][4] = {};
    if (tid < TM) sRow[tid] = 0.0f;

    // ---- A staging (global_load_lds): 2048 chunks of 16B, 2/thread ----
    // LDS chunk slot cs holds source chunk cs ^ (row&7)  (XOR swizzle)
    const int p0 = tid,        m0 = p0 >> 3, j0 = (p0 & 7) ^ (m0 & 7);
    const int p1 = 1024 + tid, m1 = p1 >> 3, j1 = (p1 & 7) ^ (m1 & 7);
    const unsigned short* aSrc0 = A + (size_t)(rowBase + m0) * K_DIM + j0 * 8;
    const unsigned short* aSrc1 = A + (size_t)(rowBase + m1) * K_DIM + j1 * 8;
    const int dOff0 = (tid & ~63) * 8;
    const int dOff1 = (1024 + (tid & ~63)) * 8;

    // ---- B staging (fp32 reg + cvt): thread owns source chunks {j_b, j_b+4}
    // of row n_b. Global reads: 32 B contiguous per lane, 128 B per 4 lanes.
    const int n_b = tid >> 2, j_b = tid & 3;
    const float4* bRow = (const float4*)(Bf + (size_t)(colBase + n_b) * K_DIM);
    const int csLo = j_b ^ BSWZ(n_b);          // dest slot for chunk j_b
    const int csHi = csLo ^ 4;                 // dest slot for chunk j_b+4
    const int bOffLo = n_b * BK + csLo * 8;    // u16 offsets within sB buffer
    const int bOffHi = n_b * BK + csHi * 8;

#define CVT_STORE(DST, A4, B4) do {                        \
        u32x4_t pk_;                                       \
        pk_[0] = cvt_pk_bf16((A4).x, (A4).y);              \
        pk_[1] = cvt_pk_bf16((A4).z, (A4).w);              \
        pk_[2] = cvt_pk_bf16((B4).x, (B4).y);              \
        pk_[3] = cvt_pk_bf16((B4).z, (B4).w);              \
        *(u32x4_t*)(DST) = pk_; } while (0)

    // prologue: stage tile 0
    {
        float4 l0 = bRow[j_b * 2], l1 = bRow[j_b * 2 + 1];
        float4 l2 = bRow[j_b * 2 + 8], l3 = bRow[j_b * 2 + 9];
        async_copy16(aSrc0, &sA[0][dOff0]);
        async_copy16(aSrc1, &sA[0][dOff1]);
        CVT_STORE(&sB[0][bOffLo], l0, l1);
        CVT_STORE(&sB[0][bOffHi], l2, l3);
    }
    __syncthreads();

    for (int kt = 0; kt < NKT; ++kt) {
        const int cur = kt & 1, nb = cur ^ 1;
        float4 l0, l1, l2, l3;
        if (kt + 1 < NKT) {
            // issue next tile's loads BEFORE computing this one (latency hides
            // under the MFMA block)
            const int f4 = (kt + 1) * (BK / 4) + j_b * 2;
            l0 = bRow[f4];     l1 = bRow[f4 + 1];
            l2 = bRow[f4 + 8]; l3 = bRow[f4 + 9];
            const int k0 = (kt + 1) * BK;
            async_copy16(aSrc0 + k0, &sA[nb][dOff0]);
            async_copy16(aSrc1 + k0, &sA[nb][dOff1]);
        }
        const unsigned short* pA = sA[cur];
        const unsigned short* pB = sB[cur];
        #pragma unroll
        for (int s = 0; s < 2; ++s) {   // two 16x16x32 K-steps
            u16x8_t af[4], bfr[4];
            #pragma unroll
            for (int r = 0; r < 4; ++r) {
                int m  = waveM * 64 + r * 16 + lr;
                int ch = (s * 4 + q) ^ (m & 7);
                af[r] = *(const u16x8_t*)(pA + m * BK + ch * 8);
            }
            #pragma unroll
            for (int c = 0; c < 4; ++c) {
                int n  = waveN * 64 + c * 16 + lr;
                int ch = (s * 4 + q) ^ BSWZ(n);
                bfr[c] = *(const u16x8_t*)(pB + n * BK + ch * 8);
            }
            #pragma unroll
            for (int r = 0; r < 4; ++r)
                #pragma unroll
                for (int c = 0; c < 4; ++c)
                    acc[r][c] = __builtin_amdgcn_mfma_f32_16x16x32_bf16(
                        __builtin_bit_cast(bf16x8_t, af[r]),
                        __builtin_bit_cast(bf16x8_t, bfr[c]),
                        acc[r][c], 0, 0, 0);
        }
        if (kt + 1 < NKT) {
            // write-late: the vmcnt wait here covers only the B regs (A's
            // lds-DMA stays in flight until the barrier)
            CVT_STORE(&sB[nb][bOffLo], l0, l1);
            CVT_STORE(&sB[nb][bOffHi], l2, l3);
        }
        __syncthreads();  // drains A DMA + orders sB writes for next iter
    }
#undef CVT_STORE

    // epilogue: C/D layout col=lane&15 (vocab n), row=quad*4+reg (token m)
    float bb[4];
    #pragma unroll
    for (int c = 0; c < 4; ++c) bb[c] = bias[colBase + waveN * 64 + c * 16 + lr];

    #pragma unroll
    for (int r = 0; r < 4; ++r) {
        float rsum[4] = {0.f, 0.f, 0.f, 0.f};
        #pragma unroll
        for (int c = 0; c < 4; ++c) {
            int gcol = colBase + waveN * 64 + c * 16 + lr;
            bool pad = (gcol == PAD_IDX);
            #pragma unroll
            for (int d = 0; d < 4; ++d) {
                int grow = rowBase + waveM * 64 + r * 16 + q * 4 + d;
                float e = pad ? 0.0f : __expf(acc[r][c][d] + bb[c]);
                // fp16 in-place: first 64000 B of the row's fp32 region
                ((unsigned short*)(out + (size_t)grow * OUT_STRIDE))[gcol] = f2h(e);
                rsum[d] += e;
            }
        }
        #pragma unroll
        for (int d = 0; d < 4; ++d) {
            float v = rsum[d];
            v += __shfl_xor(v, 1);
            v += __shfl_xor(v, 2);
            v += __shfl_xor(v, 4);
            v += __shfl_xor(v, 8);
            if (lr == 0) {
                int lrow = waveM * 64 + r * 16 + q * 4 + d;
                atomicAdd(&sRow[lrow], v);   // LDS atomic: 4x fewer global atomics
            }
        }
    }
    __syncthreads();
    if (tid < TM) atomicAdd(&rowsum[rowBase + tid], sRow[tid]);
}

// ---------------- kernel 3: in-place normalize (fp16 packed in out rows) ----------------
// UNCHANGED this round (measurement target — must enter rocprof top-5 now that
// each GEMM half is ~105 us).
__global__ __launch_bounds__(512) void finalize_kernel(
    float* __restrict__ out, const float* __restrict__ rowsum,
    const float* __restrict__ pcopy) {
    const int n   = blockIdx.x;
    const int tid = threadIdx.x;
    __shared__ unsigned short sE[N_DIM];   // 64000 B
    const float scale = (1.0f - pcopy[n]) / rowsum[n];
    const u16x8_t* src = (const u16x8_t*)(out + (size_t)n * OUT_STRIDE);
    for (int j = tid; j < N_DIM / 8; j += 512)
        *(u16x8_t*)(sE + j * 8) = src[j];
    __syncthreads();
    float4* row4 = (float4*)(out + (size_t)n * OUT_STRIDE);
    for (int j = tid; j < N_DIM / 4; j += 512) {
        u16x4_t h = *(const u16x4_t*)(sE + j * 4);
        float4 v;
        v.x = h2f(h[0]) * scale;
        v.y = h2f(h[1]) * scale;
        v.z = h2f(h[2]) * scale;
        v.w = h2f(h[3]) * scale;
        row4[j] = v;
    }
}

// ---------------- launch ----------------
extern "C" void kernel_launch(void* const* d_in, const int* in_sizes, int n_in,
                              void* d_out, int out_size, void* d_ws, size_t ws_size,
                              hipStream_t stream) {
    const float* hidden  = (const float*)d_in[0];
    const float* attn    = (const float*)d_in[1];
    const float* src_map = (const float*)d_in[2];
    const float* W       = (const float*)d_in[3];
    const float* b       = (const float*)d_in[4];
    const float* W_copy  = (const float*)d_in[5];
    const float* b_copy  = (const float*)d_in[6];
    float* out = (float*)d_out;

    // workspace layout (tiny: no W pre-cast)
    char* ws = (char*)d_ws;
    unsigned short* Hb = (unsigned short*)ws;                 //  4,194,304 B
    float* rowsum      = (float*)(ws + 4194304);              //      8,192 B
    float* pcopy       = (float*)(ws + 4194304 + 8192);       //      8,192 B

    float* out_tail = out + (size_t)M_DIM * OUT_STRIDE;       // p_copy output

    // 1. p_copy + hidden->bf16 + copy_prob + tail + rowsum zero
    pcopy_cast_kernel<<<M_DIM / 4, 256, 0, stream>>>(hidden, W_copy, b_copy, attn,
                                                     src_map, Hb, out, out_tail,
                                                     pcopy, rowsum);
    // 2. GEMM + exp + rowsum, split into two half-N dispatches (both grids are
    //    multiples of 8 for the XCD swizzle; makes finalize rocprof-visible)
    gemm_exp_kernel<<<8 * 63, 1024, 0, stream>>>(Hb, W, b, out, rowsum, 63, 0);
    gemm_exp_kernel<<<8 * 62, 1024, 0, stream>>>(Hb, W, b, out, rowsum, 62, 63);
    // 3. in-place normalize
    finalize_kernel<<<M_DIM, 512, 0, stream>>>(out, rowsum, pcopy);
}